// Round 3
// baseline (26.751 us; speedup 1.0000x reference)
//
#include <hip/hip_runtime.h>

typedef unsigned short ushort_t;
typedef unsigned int uint_t;
typedef __attribute__((ext_vector_type(8))) short short8;
typedef __attribute__((ext_vector_type(4))) float f32x4;

#define IN_DIM 256
#define OUT_DIM 256
#define BATCH 512
#define NSPL 11                 // GRID_SIZE + K bases
#define KSLOT 12                // 11 bases + 1 silu/residual slot
#define KDIM (IN_DIM * KSLOT)   // 3072
#define BM 32
#define BN 32
#define BK 128
#define LDS_STRIDE 136          // 128 + 8 pad -> 272B row stride (16B-aligned, breaks bank collisions)

__device__ __forceinline__ ushort_t f2bf(float f) {
  union { float f; uint_t i; } c; c.f = f;
  uint_t u = c.i;
  u = u + 0x7FFFu + ((u >> 16) & 1u);   // round-to-nearest-even
  return (ushort_t)(u >> 16);
}

// ---- Kernel 1: A[b][i*12+g] = B-spline bases (g<11, fp32 in, bf16 out), silu(x) (g=11) ----
__global__ __launch_bounds__(256) void build_a(const float* __restrict__ x,
                                               ushort_t* __restrict__ A) {
  const int b = blockIdx.x;
  const int i = threadIdx.x;
  const float xf = x[b * IN_DIM + i];

  // grid points g_t = -1.75 + 0.25 t, t = 0..14 ; order-0 indicators (14 wide)
  float bas[14];
#pragma unroll
  for (int t = 0; t < 14; ++t) {
    const float gt = -1.75f + 0.25f * (float)t;
    bas[t] = (xf >= gt && xf < gt + 0.25f) ? 1.0f : 0.0f;
  }
  // Cox-de Boor, uniform grid: denominators are j*spacing
#pragma unroll
  for (int j = 1; j <= 3; ++j) {
    const float inv = 1.0f / (0.25f * (float)j);
#pragma unroll
    for (int t = 0; t < 14 - j; ++t) {   // ascending in-place: reads old bas[t], old bas[t+1]
      const float gt = -1.75f + 0.25f * (float)t;
      bas[t] = (xf - gt) * inv * bas[t] +
               ((gt + 0.25f * (float)(j + 1)) - xf) * inv * bas[t + 1];
    }
  }
  const float silu = xf / (1.0f + __expf(-xf));

  ushort_t v[KSLOT];
#pragma unroll
  for (int g = 0; g < NSPL; ++g) v[g] = f2bf(bas[g]);
  v[11] = f2bf(silu);

  uint_t* dst = (uint_t*)(A + (size_t)b * KDIM + i * KSLOT);  // 24B-aligned
#pragma unroll
  for (int j = 0; j < 6; ++j) dst[j] = (uint_t)v[2 * j] | ((uint_t)v[2 * j + 1] << 16);
}

// ---- Kernel 2: W[o][i*12+g] = uw*coef (g<11), rw (g=11) ---- (fp32 in, bf16 out)
__global__ __launch_bounds__(256) void build_w(const float* __restrict__ coef,
                                               const float* __restrict__ rw,
                                               const float* __restrict__ uw,
                                               ushort_t* __restrict__ W) {
  const int o = blockIdx.x;
  const int i = threadIdx.x;
  const size_t oi = (size_t)o * IN_DIM + i;
  const float u = uw[oi];
  const float r = rw[oi];
  const float* c = coef + oi * NSPL;   // 44B contiguous per thread -> coalesced over the wave

  ushort_t v[KSLOT];
#pragma unroll
  for (int g = 0; g < NSPL; ++g) v[g] = f2bf(u * c[g]);
  v[11] = f2bf(r);

  uint_t* dst = (uint_t*)(W + oi * KSLOT);
#pragma unroll
  for (int j = 0; j < 6; ++j) dst[j] = (uint_t)v[2 * j] | ((uint_t)v[2 * j + 1] << 16);
}

// ---- Kernel 3: out[512][256] = A[512][3072] · W[256][3072]^T (bf16 MFMA, fp32 out) ----
__global__ __launch_bounds__(256) void gemm(const ushort_t* __restrict__ A,
                                            const ushort_t* __restrict__ W,
                                            float* __restrict__ out) {
  __shared__ __attribute__((aligned(16))) ushort_t As[BM * LDS_STRIDE];
  __shared__ __attribute__((aligned(16))) ushort_t Ws[BN * LDS_STRIDE];

  const int tid = threadIdx.x;
  const int lane = tid & 63;
  const int w = tid >> 6;          // 4 waves: 2x2 quadrants of 16x16
  const int wr = w >> 1, wc = w & 1;
  const int b0 = blockIdx.x * BM;
  const int o0 = blockIdx.y * BN;

  f32x4 acc = {0.f, 0.f, 0.f, 0.f};

  // staging map: chunk c in [0,512): row = c>>4, col = (c&15)*8 (16B per chunk)
  const int rA0 = tid >> 4, cA0 = (tid & 15) * 8;
  const int rA1 = (tid + 256) >> 4, cA1 = cA0;

  for (int kt = 0; kt < KDIM; kt += BK) {
    // issue global loads BEFORE the barrier: latency hides under prev MFMA phase
    short8 va0 = *(const short8*)(A + (size_t)(b0 + rA0) * KDIM + kt + cA0);
    short8 va1 = *(const short8*)(A + (size_t)(b0 + rA1) * KDIM + kt + cA1);
    short8 vw0 = *(const short8*)(W + (size_t)(o0 + rA0) * KDIM + kt + cA0);
    short8 vw1 = *(const short8*)(W + (size_t)(o0 + rA1) * KDIM + kt + cA1);

    __syncthreads();   // previous iteration's LDS reads complete
    *(short8*)(&As[rA0 * LDS_STRIDE + cA0]) = va0;
    *(short8*)(&As[rA1 * LDS_STRIDE + cA1]) = va1;
    *(short8*)(&Ws[rA0 * LDS_STRIDE + cA0]) = vw0;
    *(short8*)(&Ws[rA1 * LDS_STRIDE + cA1]) = vw1;
    __syncthreads();

    const int m = wr * 16 + (lane & 15);
    const int n = wc * 16 + (lane & 15);
    const int kl = (lane >> 4) * 8;
#pragma unroll
    for (int kk = 0; kk < BK; kk += 32) {
      short8 af = *(const short8*)(&As[m * LDS_STRIDE + kk + kl]);
      short8 bfr = *(const short8*)(&Ws[n * LDS_STRIDE + kk + kl]);
      acc = __builtin_amdgcn_mfma_f32_16x16x32_bf16(af, bfr, acc, 0, 0, 0);
    }
  }

  // C/D layout (HW-verified): col = lane&15, row = (lane>>4)*4 + reg
  const int col = o0 + wc * 16 + (lane & 15);
  const int rbase = b0 + wr * 16 + (lane >> 4) * 4;
#pragma unroll
  for (int r = 0; r < 4; ++r) {
    out[(size_t)(rbase + r) * OUT_DIM + col] = acc[r];
  }
}

extern "C" void kernel_launch(void* const* d_in, const int* in_sizes, int n_in,
                              void* d_out, int out_size, void* d_ws, size_t ws_size,
                              hipStream_t stream) {
  const float* x    = (const float*)d_in[0];
  const float* coef = (const float*)d_in[1];
  const float* rw   = (const float*)d_in[2];
  const float* uw   = (const float*)d_in[3];
  float* out = (float*)d_out;

  ushort_t* A = (ushort_t*)d_ws;                    // 512*3072*2 = 3.0 MB
  ushort_t* W = A + (size_t)BATCH * KDIM;           // 256*3072*2 = 1.5 MB (total 4.5 MB of ws)

  build_a<<<BATCH, IN_DIM, 0, stream>>>(x, A);
  build_w<<<OUT_DIM, IN_DIM, 0, stream>>>(coef, rw, uw, W);
  gemm<<<dim3(BATCH / BM, OUT_DIM / BN), 256, 0, stream>>>(A, W, out);
}

// Round 4
// 22.474 us; speedup vs baseline: 1.1903x; 1.1903x over previous
//
#include <hip/hip_runtime.h>

typedef unsigned short ushort_t;
typedef unsigned int uint_t;
typedef __attribute__((ext_vector_type(8))) short short8;
typedef __attribute__((ext_vector_type(4))) float f32x4;

#define IN_DIM 256
#define OUT_DIM 256
#define BATCH 512
#define NSPL 11                 // GRID_SIZE + K bases
#define KSLOT 12                // 11 bases + 1 silu/residual slot
#define KDIM (IN_DIM * KSLOT)   // 3072

__device__ __forceinline__ ushort_t f2bf(float f) {
  union { float f; uint_t i; } c; c.f = f;
  uint_t u = c.i;
  u = u + 0x7FFFu + ((u >> 16) & 1u);   // round-to-nearest-even
  return (ushort_t)(u >> 16);
}

// ---- Kernel 1 (fused): blocks [0,512) build A rows, blocks [512,768) build W rows ----
__global__ __launch_bounds__(256) void build_aw(const float* __restrict__ x,
                                                const float* __restrict__ coef,
                                                const float* __restrict__ rw,
                                                const float* __restrict__ uw,
                                                ushort_t* __restrict__ A,
                                                ushort_t* __restrict__ W) {
  const int bx = blockIdx.x;
  const int i = threadIdx.x;

  if (bx < BATCH) {
    // ---- A[b][i*12+g]: 11 cubic B-spline bases + silu slot ----
    const int b = bx;
    const float xf = x[b * IN_DIM + i];

    float bas[14];
#pragma unroll
    for (int t = 0; t < 14; ++t) {
      const float gt = -1.75f + 0.25f * (float)t;
      bas[t] = (xf >= gt && xf < gt + 0.25f) ? 1.0f : 0.0f;
    }
#pragma unroll
    for (int j = 1; j <= 3; ++j) {
      const float inv = 1.0f / (0.25f * (float)j);
#pragma unroll
      for (int t = 0; t < 14 - j; ++t) {   // ascending in-place: reads old bas[t], old bas[t+1]
        const float gt = -1.75f + 0.25f * (float)t;
        bas[t] = (xf - gt) * inv * bas[t] +
                 ((gt + 0.25f * (float)(j + 1)) - xf) * inv * bas[t + 1];
      }
    }
    const float silu = xf / (1.0f + __expf(-xf));

    ushort_t v[KSLOT];
#pragma unroll
    for (int g = 0; g < NSPL; ++g) v[g] = f2bf(bas[g]);
    v[11] = f2bf(silu);

    uint_t* dst = (uint_t*)(A + (size_t)b * KDIM + i * KSLOT);
#pragma unroll
    for (int j = 0; j < 6; ++j) dst[j] = (uint_t)v[2 * j] | ((uint_t)v[2 * j + 1] << 16);
  } else {
    // ---- W[o][i*12+g] = uw*coef (g<11), rw (g=11) ----
    const int o = bx - BATCH;
    const size_t oi = (size_t)o * IN_DIM + i;
    const float u = uw[oi];
    const float r = rw[oi];
    const float* c = coef + oi * NSPL;

    ushort_t v[KSLOT];
#pragma unroll
    for (int g = 0; g < NSPL; ++g) v[g] = f2bf(u * c[g]);
    v[11] = f2bf(r);

    uint_t* dst = (uint_t*)(W + oi * KSLOT);
#pragma unroll
    for (int j = 0; j < 6; ++j) dst[j] = (uint_t)v[2 * j] | ((uint_t)v[2 * j + 1] << 16);
  }
}

// ---- Kernel 2: out = A·Wᵀ. One wave per 16x16 output tile, no LDS, no barriers.
// Depth-2 register pipeline straight from L2. 512 blocks x 64 threads.
#define LOADS(AB, WB, KT)                                             \
  AB##0 = *(const short8*)(pa + (KT));                                \
  AB##1 = *(const short8*)(pa + (KT) + 32);                           \
  AB##2 = *(const short8*)(pa + (KT) + 64);                           \
  AB##3 = *(const short8*)(pa + (KT) + 96);                           \
  WB##0 = *(const short8*)(pw + (KT));                                \
  WB##1 = *(const short8*)(pw + (KT) + 32);                           \
  WB##2 = *(const short8*)(pw + (KT) + 64);                           \
  WB##3 = *(const short8*)(pw + (KT) + 96);

#define MFMAS(AB, WB)                                                 \
  acc = __builtin_amdgcn_mfma_f32_16x16x32_bf16(AB##0, WB##0, acc, 0, 0, 0); \
  acc = __builtin_amdgcn_mfma_f32_16x16x32_bf16(AB##1, WB##1, acc, 0, 0, 0); \
  acc = __builtin_amdgcn_mfma_f32_16x16x32_bf16(AB##2, WB##2, acc, 0, 0, 0); \
  acc = __builtin_amdgcn_mfma_f32_16x16x32_bf16(AB##3, WB##3, acc, 0, 0, 0);

__global__ __launch_bounds__(64, 4) void gemm(const ushort_t* __restrict__ A,
                                              const ushort_t* __restrict__ W,
                                              float* __restrict__ out) {
  const int lane = threadIdx.x;            // 0..63, one wave
  const int b0 = blockIdx.x * 16;          // M tile
  const int o0 = blockIdx.y * 16;          // N tile
  const int mn = lane & 15;
  const int kl = (lane >> 4) * 8;          // per-lane K sub-offset within a 32-chunk

  const ushort_t* pa = A + (size_t)(b0 + mn) * KDIM + kl;
  const ushort_t* pw = W + (size_t)(o0 + mn) * KDIM + kl;

  f32x4 acc = {0.f, 0.f, 0.f, 0.f};

  short8 a00, a01, a02, a03, w00, w01, w02, w03;   // stage 0 (K chunk of 128)
  short8 a10, a11, a12, a13, w10, w11, w12, w13;   // stage 1

  LOADS(a0, w0, 0)
  LOADS(a1, w1, 128)

#pragma unroll
  for (int kt = 0; kt < KDIM; kt += 256) {
    MFMAS(a0, w0)                               // consume stage 0 (loaded 1 iter ago)
    if (kt + 256 < KDIM) { LOADS(a0, w0, kt + 256) }  // refill for next iter
    MFMAS(a1, w1)
    if (kt + 384 < KDIM) { LOADS(a1, w1, kt + 384) }
  }

  // C/D layout (HW-verified): col = lane&15, row = (lane>>4)*4 + reg
  const int col = o0 + mn;
  const int rbase = b0 + (lane >> 4) * 4;
#pragma unroll
  for (int r = 0; r < 4; ++r) {
    out[(size_t)(rbase + r) * OUT_DIM + col] = acc[r];
  }
}

extern "C" void kernel_launch(void* const* d_in, const int* in_sizes, int n_in,
                              void* d_out, int out_size, void* d_ws, size_t ws_size,
                              hipStream_t stream) {
  const float* x    = (const float*)d_in[0];
  const float* coef = (const float*)d_in[1];
  const float* rw   = (const float*)d_in[2];
  const float* uw   = (const float*)d_in[3];
  float* out = (float*)d_out;

  ushort_t* A = (ushort_t*)d_ws;                    // 512*3072*2 = 3.0 MB
  ushort_t* W = A + (size_t)BATCH * KDIM;           // 256*3072*2 = 1.5 MB

  build_aw<<<BATCH + OUT_DIM, IN_DIM, 0, stream>>>(x, coef, rw, uw, A, W);
  gemm<<<dim3(BATCH / 16, OUT_DIM / 16), 64, 0, stream>>>(A, W, out);
}